// Round 12
// baseline (274.512 us; speedup 1.0000x reference)
//
#include <hip/hip_runtime.h>
#include <hip/hip_bf16.h>

#define NN 8192      // nodes
#define NE 32768     // edges
#define FD 16        // features
#define DIM 64
#define BT 4
#define RANK 512

typedef __attribute__((ext_vector_type(8))) short bf16x8;
typedef __attribute__((ext_vector_type(4))) float f32x4;

__device__ inline unsigned short f2bf(float f) {
    union { float f; unsigned u; } c; c.f = f;
    return (unsigned short)((c.u + 0x7fffu + ((c.u >> 16) & 1u)) >> 16);
}
__device__ inline float ubf(unsigned short h) {
    union { unsigned u; float f; } c; c.u = ((unsigned)h) << 16; return c.f;
}
__device__ inline float bflo(unsigned u) { union { unsigned u; float f; } c; c.u = u << 16; return c.f; }
__device__ inline float bfhi(unsigned u) { union { unsigned u; float f; } c; c.u = u & 0xffff0000u; return c.f; }

// ================================================================ k_prep: all one-time prep fused
//   [0,2048):     s = relu(x@W0.T+b0) + bf16 hi/lo split
//   [2048,2176):  degree histograms (dst float, src int)
//   [2176,6272):  per-edge hidden h32 + bond argmax
//   [6272,6784):  W2T bf16 hi/lo
//   [6784,6880):  Wih/Whh bf16 hi/lo
//   [6880,6896):  rootT bf16 hi/lo
//   [6896,6912):  b2T bf16 hi/lo
//   [6912,7168):  M[b] = V[b]@U[b]
//   [7168,7200):  zero agg (2 MB; nothing else touches agg in this dispatch)
__global__ __launch_bounds__(256) void k_prep(
    const float* __restrict__ x, const int* __restrict__ ei, const float* __restrict__ ea,
    const float* __restrict__ W0, const float* __restrict__ b0,
    const float* __restrict__ nnW1, const float* __restrict__ nnb1,
    const float* __restrict__ W2, const float* __restrict__ Wih, const float* __restrict__ Whh,
    const float* __restrict__ root, const float* __restrict__ b2,
    const float* __restrict__ U, const float* __restrict__ V,
    float* __restrict__ s, unsigned short* __restrict__ shi, unsigned short* __restrict__ slo,
    float* __restrict__ deg, int* __restrict__ srccnt,
    float* __restrict__ h32, int* __restrict__ bond,
    unsigned short* __restrict__ w2h, unsigned short* __restrict__ w2l,
    unsigned short* __restrict__ wihh, unsigned short* __restrict__ wihl,
    unsigned short* __restrict__ whhh, unsigned short* __restrict__ whhl,
    unsigned short* __restrict__ rth, unsigned short* __restrict__ rtl,
    unsigned short* __restrict__ b2th, unsigned short* __restrict__ b2tl,
    float* __restrict__ M, float* __restrict__ agg)
{
    int bid = blockIdx.x, tid = threadIdx.x;
    if (bid < 2048) {
        int gid = bid * 256 + tid;          // gid = n*64 + d
        int n = gid >> 6, d = gid & 63;
        const float4* xr = (const float4*)(x + (size_t)n * FD);
        const float4* wr = (const float4*)(W0 + d * FD);
        float4 x0 = xr[0], x1 = xr[1], x2 = xr[2], x3 = xr[3];
        float4 w0 = wr[0], w1 = wr[1], w2 = wr[2], w3 = wr[3];
        float acc = b0[d]
            + x0.x*w0.x + x0.y*w0.y + x0.z*w0.z + x0.w*w0.w
            + x1.x*w1.x + x1.y*w1.y + x1.z*w1.z + x1.w*w1.w
            + x2.x*w2.x + x2.y*w2.y + x2.z*w2.z + x2.w*w2.w
            + x3.x*w3.x + x3.y*w3.y + x3.z*w3.z + x3.w*w3.w;
        float sv = fmaxf(acc, 0.f);
        s[gid] = sv;
        unsigned short h = f2bf(sv);
        shi[gid] = h; slo[gid] = f2bf(sv - ubf(h));
    } else if (bid < 2176) {
        int e = (bid - 2048) * 256 + tid;
        atomicAdd(&deg[ei[NE + e]], 1.0f);
        atomicAdd(&srccnt[ei[e]], 1);
    } else if (bid < 6272) {
        int e = (bid - 2176) * 8 + (tid >> 5);
        int k = tid & 31;
        float a0 = ea[e * 4 + 0], a1 = ea[e * 4 + 1], a2 = ea[e * 4 + 2], a3 = ea[e * 4 + 3];
        float h = nnb1[k] + a0 * nnW1[k * 4 + 0] + a1 * nnW1[k * 4 + 1]
                          + a2 * nnW1[k * 4 + 2] + a3 * nnW1[k * 4 + 3];
        h32[e * 32 + k] = fmaxf(h, 0.f);
        if (k == 0) {
            int bi = 0; float bv = a0;
            if (a1 > bv) { bv = a1; bi = 1; }
            if (a2 > bv) { bv = a2; bi = 2; }
            if (a3 > bv) { bv = a3; bi = 3; }
            bond[e] = bi;
        }
    } else if (bid < 6784) {
        int gid = (bid - 6272) * 256 + tid;     // gid = col*64 + i
        int col = gid >> 6, i = gid & 63;
        float v = W2[(size_t)(i * 64 + (col >> 5)) * 32 + (col & 31)];
        unsigned short h = f2bf(v);
        w2h[gid] = h; w2l[gid] = f2bf(v - ubf(h));
    } else if (bid < 6880) {
        int gid = (bid - 6784) * 256 + tid;     // 24576 total
        if (gid < 12288) {
            float v = Wih[gid];
            unsigned short h = f2bf(v);
            wihh[gid] = h; wihl[gid] = f2bf(v - ubf(h));
        } else {
            int g = gid - 12288;
            float v = Whh[g];
            unsigned short h = f2bf(v);
            whhh[g] = h; whhl[g] = f2bf(v - ubf(h));
        }
    } else if (bid < 6896) {
        int gid = (bid - 6880) * 256 + tid;     // gid = o*64 + i
        int o = gid >> 6, i = gid & 63;
        float v = root[i * 64 + o];
        unsigned short h = f2bf(v);
        rth[gid] = h; rtl[gid] = f2bf(v - ubf(h));
    } else if (bid < 6912) {
        int gid = (bid - 6896) * 256 + tid;
        int o = gid >> 6, i = gid & 63;
        float v = b2[i * 64 + o];
        unsigned short h = f2bf(v);
        b2th[gid] = h; b2tl[gid] = f2bf(v - ubf(h));
    } else if (bid < 7168) {
        __shared__ float red[4][64];
        int t = bid - 6912;
        int b = t >> 6, d = t & 63;
        int chunk = tid >> 6, dp = tid & 63;
        const float* Vp = V + ((size_t)b * DIM + d) * RANK;
        const float* Up = U + (size_t)b * RANK * DIM;
        float acc = 0.f;
        for (int r = chunk * 128; r < chunk * 128 + 128; ++r)
            acc += Vp[r] * Up[(size_t)r * DIM + dp];
        red[chunk][dp] = acc;
        __syncthreads();
        if (chunk == 0)
            M[((size_t)b * DIM + d) * DIM + dp] =
                red[0][dp] + red[1][dp] + red[2][dp] + red[3][dp];
    } else {
        // zero agg: 32 jobs x 64 KB
        float4* zp = ((float4*)agg) + (size_t)(bid - 7168) * 4096;
        for (int j = tid; j < 4096; j += 256)
            zp[j] = make_float4(0.f, 0.f, 0.f, 0.f);
    }
}

// ================================================================ CSR (by src) + CSC (by dst) exclusive scans
__global__ __launch_bounds__(1024) void k_scan(const int* __restrict__ cnt,
                                               const float* __restrict__ deg,
                                               int* __restrict__ start, int* __restrict__ cursor,
                                               int* __restrict__ dstart, int* __restrict__ dcursor) {
    __shared__ int ls[1024];
    int tid = threadIdx.x;
    // ---- src scan
    {
        int v[8], tot = 0;
#pragma unroll
        for (int j = 0; j < 8; ++j) { v[j] = cnt[tid * 8 + j]; tot += v[j]; }
        ls[tid] = tot;
        __syncthreads();
        for (int off = 1; off < 1024; off <<= 1) {
            int t = (tid >= off) ? ls[tid - off] : 0;
            __syncthreads();
            ls[tid] += t;
            __syncthreads();
        }
        int run = ls[tid] - tot;
#pragma unroll
        for (int j = 0; j < 8; ++j) {
            start[tid * 8 + j] = run; cursor[tid * 8 + j] = run; run += v[j];
        }
        if (tid == 1023) start[NN] = run;
    }
    __syncthreads();
    // ---- dst scan (counts from float deg histogram)
    {
        int v[8], tot = 0;
#pragma unroll
        for (int j = 0; j < 8; ++j) { v[j] = (int)deg[tid * 8 + j]; tot += v[j]; }
        ls[tid] = tot;
        __syncthreads();
        for (int off = 1; off < 1024; off <<= 1) {
            int t = (tid >= off) ? ls[tid - off] : 0;
            __syncthreads();
            ls[tid] += t;
            __syncthreads();
        }
        int run = ls[tid] - tot;
#pragma unroll
        for (int j = 0; j < 8; ++j) {
            dstart[tid * 8 + j] = run; dcursor[tid * 8 + j] = run; run += v[j];
        }
        if (tid == 1023) dstart[NN] = run;
    }
}

__global__ __launch_bounds__(256) void k_scatter(const int* __restrict__ ei,
                                                 int* __restrict__ cursor, int* __restrict__ eord,
                                                 int* __restrict__ dcursor, int* __restrict__ eordD) {
    int e = blockIdx.x * 256 + threadIdx.x;
    int s_ = ei[e], d_ = ei[NE + e];
    eord[atomicAdd(&cursor[s_], 1)] = e;
    eordD[atomicAdd(&dcursor[d_], 1)] = e;
}

// ================================================================ A = s @ W2 (+ cbuf = s @ b2), split-bf16 MFMA
// grid (64, 17): y<16 -> 128x128 A tile (4 waves, each 64x64); y==16 -> cbuf.
__global__ __launch_bounds__(256) void k_gemm_A(const unsigned short* __restrict__ sh,
                                                const unsigned short* __restrict__ sl,
                                                const unsigned short* __restrict__ wh,
                                                const unsigned short* __restrict__ wl,
                                                const unsigned short* __restrict__ b2th,
                                                const unsigned short* __restrict__ b2tl,
                                                unsigned short* __restrict__ A,
                                                float* __restrict__ cbuf) {
    int tid = threadIdx.x, wid = tid >> 6, lane = tid & 63;
    int lr = lane & 15, kg = lane >> 4;
    if (blockIdx.y == 16) {
        int rbase = blockIdx.x * 128 + wid * 32;
        f32x4 acc[2][4] = {};
#pragma unroll
        for (int kb = 0; kb < 2; ++kb) {
            bf16x8 ah[2], al[2];
#pragma unroll
            for (int mi = 0; mi < 2; ++mi) {
                size_t off = (size_t)(rbase + mi * 16 + lr) * 64 + kb * 32 + kg * 8;
                ah[mi] = *(const bf16x8*)(sh + off);
                al[mi] = *(const bf16x8*)(sl + off);
            }
#pragma unroll
            for (int ni = 0; ni < 4; ++ni) {
                size_t offB = (size_t)(ni * 16 + lr) * 64 + kb * 32 + kg * 8;
                bf16x8 bh = *(const bf16x8*)(b2th + offB);
                bf16x8 bl = *(const bf16x8*)(b2tl + offB);
#pragma unroll
                for (int mi = 0; mi < 2; ++mi) {
                    acc[mi][ni] = __builtin_amdgcn_mfma_f32_16x16x32_bf16(ah[mi], bh, acc[mi][ni], 0, 0, 0);
                    acc[mi][ni] = __builtin_amdgcn_mfma_f32_16x16x32_bf16(ah[mi], bl, acc[mi][ni], 0, 0, 0);
                    acc[mi][ni] = __builtin_amdgcn_mfma_f32_16x16x32_bf16(al[mi], bh, acc[mi][ni], 0, 0, 0);
                }
            }
        }
#pragma unroll
        for (int mi = 0; mi < 2; ++mi)
#pragma unroll
            for (int r = 0; r < 4; ++r)
#pragma unroll
                for (int ni = 0; ni < 4; ++ni)
                    cbuf[(size_t)(rbase + mi * 16 + kg * 4 + r) * 64 + ni * 16 + lr] = acc[mi][ni][r];
        return;
    }
    int mbase = blockIdx.x * 128 + (wid >> 1) * 64;
    int nbase = blockIdx.y * 128 + (wid & 1) * 64;
    f32x4 acc[4][4] = {};
#pragma unroll
    for (int kb = 0; kb < 2; ++kb) {
        bf16x8 ah[4], al[4], bh[4], bl[4];
#pragma unroll
        for (int mi = 0; mi < 4; ++mi) {
            size_t off = (size_t)(mbase + mi * 16 + lr) * 64 + kb * 32 + kg * 8;
            ah[mi] = *(const bf16x8*)(sh + off);
            al[mi] = *(const bf16x8*)(sl + off);
        }
#pragma unroll
        for (int ni = 0; ni < 4; ++ni) {
            size_t off = (size_t)(nbase + ni * 16 + lr) * 64 + kb * 32 + kg * 8;
            bh[ni] = *(const bf16x8*)(wh + off);
            bl[ni] = *(const bf16x8*)(wl + off);
        }
#pragma unroll
        for (int mi = 0; mi < 4; ++mi)
#pragma unroll
            for (int ni = 0; ni < 4; ++ni) {
                acc[mi][ni] = __builtin_amdgcn_mfma_f32_16x16x32_bf16(ah[mi], bh[ni], acc[mi][ni], 0, 0, 0);
                acc[mi][ni] = __builtin_amdgcn_mfma_f32_16x16x32_bf16(ah[mi], bl[ni], acc[mi][ni], 0, 0, 0);
                acc[mi][ni] = __builtin_amdgcn_mfma_f32_16x16x32_bf16(al[mi], bh[ni], acc[mi][ni], 0, 0, 0);
            }
    }
#pragma unroll
    for (int mi = 0; mi < 4; ++mi)
#pragma unroll
        for (int r = 0; r < 4; ++r) {
            size_t row = (size_t)(mbase + mi * 16 + kg * 4 + r) * 2048;
#pragma unroll
            for (int ni = 0; ni < 4; ++ni)
                A[row + nbase + ni * 16 + lr] = f2bf(acc[mi][ni][r]);
        }
}

// ================================================================ CSR edge message + scatter
__global__ __launch_bounds__(256) void k_edge(const int* __restrict__ ei,
                                              const int* __restrict__ startp,
                                              const int* __restrict__ srccnt,
                                              const int* __restrict__ eord,
                                              const float* __restrict__ h32,
                                              const unsigned short* __restrict__ A,
                                              const float* __restrict__ cbuf,
                                              float* __restrict__ agg) {
    int tid = threadIdx.x, wid = tid >> 6, o = tid & 63;
    int n = blockIdx.x * 4 + wid;
    int cnt = srccnt[n];
    if (cnt == 0) return;
    int beg = startp[n];
    float cv = cbuf[(size_t)n * DIM + o];
    const uint4* Ap = (const uint4*)(A + (size_t)n * 2048 + o * 32);
    uint4 a0 = Ap[0], a1 = Ap[1], a2 = Ap[2], a3 = Ap[3];
    for (int i = beg; i < beg + cnt; ++i) {
        int e = eord[i];
        int dst = ei[NE + e];
        const float4* hp = (const float4*)(h32 + (size_t)e * 32);
        float acc = cv;
        float4 hA = hp[0], hB = hp[1];
        acc += hA.x*bflo(a0.x) + hA.y*bfhi(a0.x) + hA.z*bflo(a0.y) + hA.w*bfhi(a0.y)
             + hB.x*bflo(a0.z) + hB.y*bfhi(a0.z) + hB.z*bflo(a0.w) + hB.w*bfhi(a0.w);
        hA = hp[2]; hB = hp[3];
        acc += hA.x*bflo(a1.x) + hA.y*bfhi(a1.x) + hA.z*bflo(a1.y) + hA.w*bfhi(a1.y)
             + hB.x*bflo(a1.z) + hB.y*bfhi(a1.z) + hB.z*bflo(a1.w) + hB.w*bfhi(a1.w);
        hA = hp[4]; hB = hp[5];
        acc += hA.x*bflo(a2.x) + hA.y*bfhi(a2.x) + hA.z*bflo(a2.y) + hA.w*bfhi(a2.y)
             + hB.x*bflo(a2.z) + hB.y*bfhi(a2.z) + hB.z*bflo(a2.w) + hB.w*bfhi(a2.w);
        hA = hp[6]; hB = hp[7];
        acc += hA.x*bflo(a3.x) + hA.y*bfhi(a3.x) + hA.z*bflo(a3.y) + hA.w*bfhi(a3.y)
             + hB.x*bflo(a3.z) + hB.y*bfhi(a3.z) + hB.z*bflo(a3.w) + hB.w*bfhi(a3.w);
        atomicAdd(&agg[(size_t)dst * DIM + o], acc);
    }
}

// ================================================================ fused update, 4 waves/block;
// on last iteration also produces oe/oc (edges_out folded) and skips s writes.
__global__ __launch_bounds__(256) void k_upd(
    float* __restrict__ s, unsigned short* __restrict__ shi, unsigned short* __restrict__ slo,
    float* __restrict__ agg, const float* __restrict__ deg, const float* __restrict__ conv_b,
    const unsigned short* __restrict__ rth, const unsigned short* __restrict__ rtl,
    const unsigned short* __restrict__ wihh, const unsigned short* __restrict__ wihl,
    const unsigned short* __restrict__ whhh, const unsigned short* __restrict__ whhl,
    const float* __restrict__ bih, const float* __restrict__ bhh,
    const float* __restrict__ x, const float* __restrict__ W1l, const float* __restrict__ b1l,
    const float* __restrict__ WUp, const float* __restrict__ bUp,
    float* __restrict__ oe, float* __restrict__ oc, int last)
{
    __shared__ unsigned short mh_l[16 * 64];
    __shared__ unsigned short ml_l[16 * 64];
    __shared__ float gl[16 * 384];
    __shared__ float oel[64];
    int tid = threadIdx.x;
    int wid = tid >> 6, lane = tid & 63;
    int lr = lane & 15, kg = lane >> 4;
    int m0 = blockIdx.x * 16;

    bf16x8 sa_h[2], sa_l[2];
#pragma unroll
    for (int kb = 0; kb < 2; ++kb) {
        size_t off = (size_t)(m0 + lr) * 64 + kb * 32 + kg * 8;
        sa_h[kb] = *(const bf16x8*)(shi + off);
        sa_l[kb] = *(const bf16x8*)(slo + off);
    }

    // ---- phase 1: m strip ni = wid
    f32x4 macc = {};
#pragma unroll
    for (int kb = 0; kb < 2; ++kb) {
        size_t offB = (size_t)(wid * 16 + lr) * 64 + kb * 32 + kg * 8;
        bf16x8 bh = *(const bf16x8*)(rth + offB);
        bf16x8 bl = *(const bf16x8*)(rtl + offB);
        macc = __builtin_amdgcn_mfma_f32_16x16x32_bf16(sa_h[kb], bh, macc, 0, 0, 0);
        macc = __builtin_amdgcn_mfma_f32_16x16x32_bf16(sa_h[kb], bl, macc, 0, 0, 0);
        macc = __builtin_amdgcn_mfma_f32_16x16x32_bf16(sa_l[kb], bh, macc, 0, 0, 0);
    }
#pragma unroll
    for (int r = 0; r < 4; ++r) {
        int row = m0 + kg * 4 + r;
        float inv = 1.f / fmaxf(deg[row], 1.f);
        int col = wid * 16 + lr;
        size_t idx = (size_t)row * 64 + col;
        float v = macc[r] + agg[idx] * inv + conv_b[col];
        agg[idx] = 0.f;                       // self-zero for next iteration
        v = fmaxf(v, 0.f);
        unsigned short h = f2bf(v);
        int loff = (kg * 4 + r) * 64 + col;
        mh_l[loff] = h; ml_l[loff] = f2bf(v - ubf(h));
    }
    __syncthreads();

    // ---- phase 2: 3 gi + 3 gh strips per wave
    bf16x8 ma_h[2], ma_l[2];
#pragma unroll
    for (int kb = 0; kb < 2; ++kb) {
        int loff = lr * 64 + kb * 32 + kg * 8;
        ma_h[kb] = *(const bf16x8*)(mh_l + loff);
        ma_l[kb] = *(const bf16x8*)(ml_l + loff);
    }
    f32x4 gacc[3] = {}, hacc[3] = {};
#pragma unroll
    for (int kb = 0; kb < 2; ++kb)
#pragma unroll
        for (int j = 0; j < 3; ++j) {
            int ni = wid * 3 + j;            // 0..11
            size_t offB = (size_t)(ni * 16 + lr) * 64 + kb * 32 + kg * 8;
            bf16x8 bh = *(const bf16x8*)(wihh + offB);
            bf16x8 bl = *(const bf16x8*)(wihl + offB);
            gacc[j] = __builtin_amdgcn_mfma_f32_16x16x32_bf16(ma_h[kb], bh, gacc[j], 0, 0, 0);
            gacc[j] = __builtin_amdgcn_mfma_f32_16x16x32_bf16(ma_h[kb], bl, gacc[j], 0, 0, 0);
            gacc[j] = __builtin_amdgcn_mfma_f32_16x16x32_bf16(ma_l[kb], bh, gacc[j], 0, 0, 0);
            bf16x8 ch = *(const bf16x8*)(whhh + offB);
            bf16x8 cl = *(const bf16x8*)(whhl + offB);
            hacc[j] = __builtin_amdgcn_mfma_f32_16x16x32_bf16(sa_h[kb], ch, hacc[j], 0, 0, 0);
            hacc[j] = __builtin_amdgcn_mfma_f32_16x16x32_bf16(sa_h[kb], cl, hacc[j], 0, 0, 0);
            hacc[j] = __builtin_amdgcn_mfma_f32_16x16x32_bf16(sa_l[kb], ch, hacc[j], 0, 0, 0);
        }
#pragma unroll
    for (int j = 0; j < 3; ++j)
#pragma unroll
        for (int r = 0; r < 4; ++r) {
            int row = kg * 4 + r;
            int col = (wid * 3 + j) * 16 + lr;      // 0..191
            gl[row * 384 + col] = gacc[j][r];
            gl[row * 384 + 192 + col] = hacc[j][r];
        }
    __syncthreads();

    // ---- phase 3: GRU elementwise; stash s_new into gl[row*384+d] (own ir slot)
#pragma unroll
    for (int k = 0; k < 4; ++k) {
        int item = tid + k * 256;           // 0..1023
        int row = item >> 6, d = item & 63;
        size_t idx = (size_t)(m0 + row) * 64 + d;
        const float* gr = gl + row * 384;
        float ir = gr[d], iz = gr[64 + d], in_ = gr[128 + d];
        float hr_ = gr[192 + d], hz = gr[256 + d], hn = gr[320 + d];
        float hv = s[idx];
        float rg = 1.f / (1.f + expf(-(ir + bih[d] + hr_ + bhh[d])));
        float z  = 1.f / (1.f + expf(-(iz + bih[64 + d] + hz + bhh[64 + d])));
        float nv = tanhf(in_ + bih[128 + d] + rg * (hn + bhh[128 + d]));
        float nh = (1.f - z) * nv + z * hv;
        if (!last) {
            s[idx] = nh;
            unsigned short hb = f2bf(nh);
            shi[idx] = hb; slo[idx] = f2bf(nh - ubf(hb));
        }
        gl[row * 384 + d] = nh;             // safe: this thread's own ir slot, already read
    }
    if (!last) return;
    __syncthreads();

    // ---- folded edges_out: oe = relu(s@W1l.T + b1l), oc = combine
    {
        int node16 = tid >> 4, j = tid & 15, t = j & 3, q = j >> 2;
        float p = 0.f;
#pragma unroll
        for (int i = 0; i < 16; ++i)
            p += gl[node16 * 384 + q * 16 + i] * W1l[t * 64 + q * 16 + i];
        p += __shfl_xor(p, 4);
        p += __shfl_xor(p, 8);
        if (q == 0) {
            float v = fmaxf(p + b1l[t], 0.f);
            oel[node16 * 4 + t] = v;
            oe[(size_t)(m0 + node16) * 4 + t] = v;
        }
    }
    __syncthreads();
#pragma unroll
    for (int k = 0; k < 4; ++k) {
        int item = tid + k * 256;
        int row = item >> 6, d = item & 63;
        int node = m0 + row;
        float sval = gl[row * 384 + d];
        float ocv;
        if (x[(size_t)node * FD] == 2.0f) {
            ocv = bUp[d];
#pragma unroll
            for (int t = 0; t < 4; ++t) ocv += oel[row * 4 + t] * WUp[d * 4 + t];
        } else {
            ocv = sval;
        }
        oc[(size_t)node * DIM + d] = ocv;
    }
}

// ================================================================ fused FGNet (CSC gather) + final log_softmax
// wave per dst node: in-edges from eordD, me = oc[src]@M[bond] accumulated
// in-register via shfl broadcast (no atomics, no fg_agg buffer).
__global__ __launch_bounds__(256) void k_fg(const int* __restrict__ ei,
                                            const int* __restrict__ bond,
                                            const int* __restrict__ dstart,
                                            const int* __restrict__ eordD,
                                            const float* __restrict__ oc,
                                            const float* __restrict__ M,
                                            const float* __restrict__ deg,
                                            const float* __restrict__ oe,
                                            const float* __restrict__ WDown,
                                            const float* __restrict__ bDown,
                                            const float* __restrict__ weight_e,
                                            const float* __restrict__ linWe,
                                            const float* __restrict__ linbe,
                                            float* __restrict__ out) {
    int tid = threadIdx.x, wid = tid >> 6, lane = tid & 63;
    int node = blockIdx.x * 4 + wid;
    float degf = deg[node];
    int cnt = (int)degf;
    int beg = dstart[node];
    float acc = 0.f;
    for (int i = 0; i < cnt; ++i) {
        int e = eordD[beg + i];
        int src = ei[e];
        int b = bond[e];
        float ocv = oc[(size_t)src * DIM + lane];
        const float* Mp = M + b * DIM * DIM;
#pragma unroll
        for (int d = 0; d < 64; ++d)
            acc += __shfl(ocv, d) * Mp[d * 64 + lane];
    }
    float mf = fmaxf(acc / fmaxf(degf, 1.f), 0.f);
    float mte[4];
#pragma unroll
    for (int t = 0; t < 4; ++t) {
        float p = mf * WDown[t * 64 + lane];
#pragma unroll
        for (int off = 32; off; off >>= 1) p += __shfl_xor(p, off);
        mte[t] = p + bDown[t];
    }
    float val[4];
    float mx = -1e30f;
#pragma unroll
    for (int t = 0; t < 4; ++t) {
        float a2 = linbe[t];
#pragma unroll
        for (int t2 = 0; t2 < 4; ++t2) a2 += weight_e[t2] * mte[t2] * linWe[t * 4 + t2];
        val[t] = oe[(size_t)node * 4 + t] + fmaxf(a2, 0.f);
        mx = fmaxf(mx, val[t]);
    }
    float lse = 0.f;
#pragma unroll
    for (int t = 0; t < 4; ++t) lse += expf(val[t] - mx);
    lse = logf(lse);
    if (lane < 4) out[(size_t)node * 4 + lane] = val[lane] - mx - lse;
}

// ================================================================ host
extern "C" void kernel_launch(void* const* d_in, const int* in_sizes, int n_in,
                              void* d_out, int out_size, void* d_ws, size_t ws_size,
                              hipStream_t stream) {
    const float* x       = (const float*)d_in[0];
    const int*   ei      = (const int*)  d_in[1];
    const float* ea      = (const float*)d_in[2];
    const float* W0      = (const float*)d_in[3];
    const float* b0      = (const float*)d_in[4];
    const float* nnW1    = (const float*)d_in[5];
    const float* nnb1    = (const float*)d_in[6];
    const float* nnW2    = (const float*)d_in[7];
    const float* nnb2    = (const float*)d_in[8];
    const float* root    = (const float*)d_in[9];
    const float* conv_b  = (const float*)d_in[10];
    const float* Wih     = (const float*)d_in[11];
    const float* Whh     = (const float*)d_in[12];
    const float* bih     = (const float*)d_in[13];
    const float* bhh     = (const float*)d_in[14];
    const float* W1l     = (const float*)d_in[15];
    const float* b1l     = (const float*)d_in[16];
    const float* WUp     = (const float*)d_in[17];
    const float* bUp     = (const float*)d_in[18];
    const float* WDown   = (const float*)d_in[19];
    const float* bDown   = (const float*)d_in[20];
    const float* U       = (const float*)d_in[21];
    const float* V       = (const float*)d_in[22];
    // d_in[23..25] weight/linW/linb: dead code (node-'out' branch never reaches output)
    const float* weight_e= (const float*)d_in[26];
    const float* linWe   = (const float*)d_in[27];
    const float* linbe   = (const float*)d_in[28];
    float* out = (float*)d_out;

    char* ws = (char*)d_ws;
    size_t off = 0;
    auto alloc = [&](size_t bytes) { size_t o = off; off = (off + bytes + 255) & ~(size_t)255; return o; };
    float* deg    = (float*)(ws + alloc((size_t)NN * 4));
    int*   srccnt = (int*)  (ws + alloc((size_t)NN * 4));            // adjacent to deg (one memset)
    float* agg    = (float*)(ws + alloc((size_t)NN * DIM * 4));
    float* s      = (float*)(ws + alloc((size_t)NN * DIM * 4));
    unsigned short* shi = (unsigned short*)(ws + alloc((size_t)NN * DIM * 2));
    unsigned short* slo = (unsigned short*)(ws + alloc((size_t)NN * DIM * 2));
    float* cbuf   = (float*)(ws + alloc((size_t)NN * DIM * 4));
    float* h32    = (float*)(ws + alloc((size_t)NE * 32 * 4));
    int*   bond   = (int*)  (ws + alloc((size_t)NE * 4));
    int*   startp = (int*)  (ws + alloc((size_t)(NN + 1) * 4));      // +1 sentinel
    int*   cursor = (int*)  (ws + alloc((size_t)NN * 4));
    int*   eord   = (int*)  (ws + alloc((size_t)NE * 4));
    int*   dstart = (int*)  (ws + alloc((size_t)(NN + 1) * 4));
    int*   dcursor= (int*)  (ws + alloc((size_t)NN * 4));
    int*   eordD  = (int*)  (ws + alloc((size_t)NE * 4));
    float* oe     = (float*)(ws + alloc((size_t)NN * 4 * 4));
    float* oc     = (float*)(ws + alloc((size_t)NN * DIM * 4));
    float* Mbuf   = (float*)(ws + alloc((size_t)BT * DIM * DIM * 4));
    unsigned short* w2h = (unsigned short*)(ws + alloc((size_t)2048 * 64 * 2));
    unsigned short* w2l = (unsigned short*)(ws + alloc((size_t)2048 * 64 * 2));
    unsigned short* wihh = (unsigned short*)(ws + alloc((size_t)192 * 64 * 2));
    unsigned short* wihl = (unsigned short*)(ws + alloc((size_t)192 * 64 * 2));
    unsigned short* whhh = (unsigned short*)(ws + alloc((size_t)192 * 64 * 2));
    unsigned short* whhl = (unsigned short*)(ws + alloc((size_t)192 * 64 * 2));
    unsigned short* rth  = (unsigned short*)(ws + alloc((size_t)64 * 64 * 2));
    unsigned short* rtl  = (unsigned short*)(ws + alloc((size_t)64 * 64 * 2));
    unsigned short* b2th = (unsigned short*)(ws + alloc((size_t)64 * 64 * 2));
    unsigned short* b2tl = (unsigned short*)(ws + alloc((size_t)64 * 64 * 2));
    unsigned short* Abuf = (unsigned short*)(ws + alloc((size_t)NN * 2048 * 2));
    (void)n_in; (void)in_sizes; (void)out_size; (void)ws_size;

    hipMemsetAsync(deg, 0, (size_t)2 * NN * 4, stream);              // deg + srccnt only

    k_prep<<<7200, 256, 0, stream>>>(x, ei, ea, W0, b0, nnW1, nnb1,
                                     nnW2, Wih, Whh, root, nnb2, U, V,
                                     s, shi, slo, deg, srccnt, h32, bond,
                                     w2h, w2l, wihh, wihl, whhh, whhl,
                                     rth, rtl, b2th, b2tl, Mbuf, agg);
    k_scan<<<1, 1024, 0, stream>>>(srccnt, deg, startp, cursor, dstart, dcursor);
    k_scatter<<<NE / 256, 256, 0, stream>>>(ei, cursor, eord, dcursor, eordD);

    for (int it = 0; it < 3; ++it) {
        k_gemm_A<<<dim3(NN / 128, 17), 256, 0, stream>>>(shi, slo, w2h, w2l, b2th, b2tl,
                                                         Abuf, cbuf);
        k_edge<<<NN / 4, 256, 0, stream>>>(ei, startp, srccnt, eord, h32, Abuf, cbuf, agg);
        k_upd<<<NN / 16, 256, 0, stream>>>(s, shi, slo, agg, deg, conv_b,
                                           rth, rtl, wihh, wihl, whhh, whhl, bih, bhh,
                                           x, W1l, b1l, WUp, bUp, oe, oc, it == 2);
    }

    k_fg<<<NN / 4, 256, 0, stream>>>(ei, bond, dstart, eordD, oc, Mbuf, deg,
                                     oe, WDown, bDown, weight_e, linWe, linbe, out);
}

// Round 13
// 230.176 us; speedup vs baseline: 1.1926x; 1.1926x over previous
//
#include <hip/hip_runtime.h>
#include <hip/hip_bf16.h>

#define NN 8192      // nodes
#define NE 32768     // edges
#define FD 16        // features
#define DIM 64
#define BT 4
#define RANK 512

typedef __attribute__((ext_vector_type(8))) short bf16x8;
typedef __attribute__((ext_vector_type(4))) float f32x4;

__device__ inline unsigned short f2bf(float f) {
    union { float f; unsigned u; } c; c.f = f;
    return (unsigned short)((c.u + 0x7fffu + ((c.u >> 16) & 1u)) >> 16);
}
__device__ inline float ubf(unsigned short h) {
    union { unsigned u; float f; } c; c.u = ((unsigned)h) << 16; return c.f;
}
__device__ inline float bflo(unsigned u) { union { unsigned u; float f; } c; c.u = u << 16; return c.f; }
__device__ inline float bfhi(unsigned u) { union { unsigned u; float f; } c; c.u = u & 0xffff0000u; return c.f; }

// ================================================================ k_prep: one-time prep, compacted grid (2016 blocks)
//   [0,512):      s = relu(x@W0.T+b0) + bf16 hi/lo split      (1024 elems/block)
//   [512,1536):   h32 + bond + deg/srccnt histograms          (32 edges/block)
//   [1536,1664):  W2T bf16 hi/lo                              (1024/block)
//   [1664,1688):  Wih/Whh bf16 hi/lo                          (1024/block)
//   [1688,1696):  rootT + b2T bf16 hi/lo                      (1024/block)
//   [1696,1952):  M[b] = V[b]@U[b]
//   [1952,2016):  zero agg+fg_agg (4 MB contiguous; untouched elsewhere here)
__global__ __launch_bounds__(256) void k_prep(
    const float* __restrict__ x, const int* __restrict__ ei, const float* __restrict__ ea,
    const float* __restrict__ W0, const float* __restrict__ b0,
    const float* __restrict__ nnW1, const float* __restrict__ nnb1,
    const float* __restrict__ W2, const float* __restrict__ Wih, const float* __restrict__ Whh,
    const float* __restrict__ root, const float* __restrict__ b2,
    const float* __restrict__ U, const float* __restrict__ V,
    float* __restrict__ s, unsigned short* __restrict__ shi, unsigned short* __restrict__ slo,
    float* __restrict__ deg, int* __restrict__ srccnt,
    float* __restrict__ h32, int* __restrict__ bond,
    unsigned short* __restrict__ w2h, unsigned short* __restrict__ w2l,
    unsigned short* __restrict__ wihh, unsigned short* __restrict__ wihl,
    unsigned short* __restrict__ whhh, unsigned short* __restrict__ whhl,
    unsigned short* __restrict__ rth, unsigned short* __restrict__ rtl,
    unsigned short* __restrict__ b2th, unsigned short* __restrict__ b2tl,
    float* __restrict__ M, float* __restrict__ agg)
{
    int bid = blockIdx.x, tid = threadIdx.x;
    if (bid < 512) {
#pragma unroll
        for (int q = 0; q < 4; ++q) {
            int gid = bid * 1024 + q * 256 + tid;   // n*64 + d
            int n = gid >> 6, d = gid & 63;
            const float4* xr = (const float4*)(x + (size_t)n * FD);
            const float4* wr = (const float4*)(W0 + d * FD);
            float4 x0 = xr[0], x1 = xr[1], x2 = xr[2], x3 = xr[3];
            float4 w0 = wr[0], w1 = wr[1], w2 = wr[2], w3 = wr[3];
            float acc = b0[d]
                + x0.x*w0.x + x0.y*w0.y + x0.z*w0.z + x0.w*w0.w
                + x1.x*w1.x + x1.y*w1.y + x1.z*w1.z + x1.w*w1.w
                + x2.x*w2.x + x2.y*w2.y + x2.z*w2.z + x2.w*w2.w
                + x3.x*w3.x + x3.y*w3.y + x3.z*w3.z + x3.w*w3.w;
            float sv = fmaxf(acc, 0.f);
            s[gid] = sv;
            unsigned short h = f2bf(sv);
            shi[gid] = h; slo[gid] = f2bf(sv - ubf(h));
        }
    } else if (bid < 1536) {
        int eb = (bid - 512) * 32;
#pragma unroll
        for (int p = 0; p < 4; ++p) {
            int e = eb + p * 8 + (tid >> 5);
            int k = tid & 31;
            float a0 = ea[e * 4 + 0], a1 = ea[e * 4 + 1], a2 = ea[e * 4 + 2], a3 = ea[e * 4 + 3];
            float h = nnb1[k] + a0 * nnW1[k * 4 + 0] + a1 * nnW1[k * 4 + 1]
                              + a2 * nnW1[k * 4 + 2] + a3 * nnW1[k * 4 + 3];
            h32[e * 32 + k] = fmaxf(h, 0.f);
            if (k == 0) {
                int bi = 0; float bv = a0;
                if (a1 > bv) { bv = a1; bi = 1; }
                if (a2 > bv) { bv = a2; bi = 2; }
                if (a3 > bv) { bv = a3; bi = 3; }
                bond[e] = bi;
                atomicAdd(&deg[ei[NE + e]], 1.0f);
                atomicAdd(&srccnt[ei[e]], 1);
            }
        }
    } else if (bid < 1664) {
#pragma unroll
        for (int q = 0; q < 4; ++q) {
            int gid = (bid - 1536) * 1024 + q * 256 + tid;  // col*64 + i, 131072 total
            int col = gid >> 6, i = gid & 63;
            float v = W2[(size_t)(i * 64 + (col >> 5)) * 32 + (col & 31)];
            unsigned short h = f2bf(v);
            w2h[gid] = h; w2l[gid] = f2bf(v - ubf(h));
        }
    } else if (bid < 1688) {
#pragma unroll
        for (int q = 0; q < 4; ++q) {
            int gid = (bid - 1664) * 1024 + q * 256 + tid;  // 24576 total
            if (gid < 12288) {
                float v = Wih[gid];
                unsigned short h = f2bf(v);
                wihh[gid] = h; wihl[gid] = f2bf(v - ubf(h));
            } else {
                int g = gid - 12288;
                float v = Whh[g];
                unsigned short h = f2bf(v);
                whhh[g] = h; whhl[g] = f2bf(v - ubf(h));
            }
        }
    } else if (bid < 1696) {
#pragma unroll
        for (int q = 0; q < 4; ++q) {
            int gid = (bid - 1688) * 1024 + q * 256 + tid;  // 8192 total
            if (gid < 4096) {
                int o = gid >> 6, i = gid & 63;
                float v = root[i * 64 + o];
                unsigned short h = f2bf(v);
                rth[gid] = h; rtl[gid] = f2bf(v - ubf(h));
            } else {
                int g = gid - 4096;
                int o = g >> 6, i = g & 63;
                float v = b2[i * 64 + o];
                unsigned short h = f2bf(v);
                b2th[g] = h; b2tl[g] = f2bf(v - ubf(h));
            }
        }
    } else if (bid < 1952) {
        __shared__ float red[4][64];
        int t = bid - 1696;
        int b = t >> 6, d = t & 63;
        int chunk = tid >> 6, dp = tid & 63;
        const float* Vp = V + ((size_t)b * DIM + d) * RANK;
        const float* Up = U + (size_t)b * RANK * DIM;
        float acc = 0.f;
        for (int r = chunk * 128; r < chunk * 128 + 128; ++r)
            acc += Vp[r] * Up[(size_t)r * DIM + dp];
        red[chunk][dp] = acc;
        __syncthreads();
        if (chunk == 0)
            M[((size_t)b * DIM + d) * DIM + dp] =
                red[0][dp] + red[1][dp] + red[2][dp] + red[3][dp];
    } else {
        // zero agg + fg_agg: 64 blocks x 64 KB (4 MB contiguous from agg)
        float4* zp = ((float4*)agg) + (size_t)(bid - 1952) * 4096;
#pragma unroll
        for (int q = 0; q < 16; ++q)
            zp[q * 256 + tid] = make_float4(0.f, 0.f, 0.f, 0.f);
    }
}

// ================================================================ CSR exclusive scan (wave-shuffle, 2 barriers)
__global__ __launch_bounds__(1024) void k_scan(const int* __restrict__ cnt,
                                               int* __restrict__ start, int* __restrict__ cursor) {
    __shared__ int wsum[16];
    int tid = threadIdx.x, lane = tid & 63, wv = tid >> 6;
    int v[8], tot = 0;
#pragma unroll
    for (int j = 0; j < 8; ++j) { v[j] = cnt[tid * 8 + j]; tot += v[j]; }
    int incl = tot;
#pragma unroll
    for (int off = 1; off < 64; off <<= 1) {
        int t = __shfl_up(incl, off);
        if (lane >= off) incl += t;
    }
    if (lane == 63) wsum[wv] = incl;
    __syncthreads();
    if (wv == 0) {
        int wval = (lane < 16) ? wsum[lane] : 0;
        int winc = wval;
#pragma unroll
        for (int off = 1; off < 16; off <<= 1) {
            int t = __shfl_up(winc, off);
            if (lane >= off) winc += t;
        }
        if (lane < 16) wsum[lane] = winc - wval;   // exclusive wave base
    }
    __syncthreads();
    int run = wsum[wv] + incl - tot;   // exclusive base for this thread
#pragma unroll
    for (int j = 0; j < 8; ++j) {
        start[tid * 8 + j] = run; cursor[tid * 8 + j] = run; run += v[j];
    }
    if (tid == 1023) start[NN] = run;  // sentinel = NE
}

__global__ __launch_bounds__(256) void k_scatter(const int* __restrict__ ei,
                                                 int* __restrict__ cursor, int* __restrict__ eord) {
    int e = blockIdx.x * 256 + threadIdx.x;
    int pos = atomicAdd(&cursor[ei[e]], 1);
    eord[pos] = e;
}

// ================================================================ A = s @ W2 (+ cbuf = s @ b2), split-bf16 MFMA
// grid (64, 17): y<16 -> 128x128 A tile (4 waves, each 64x64); y==16 -> cbuf.
__global__ __launch_bounds__(256) void k_gemm_A(const unsigned short* __restrict__ sh,
                                                const unsigned short* __restrict__ sl,
                                                const unsigned short* __restrict__ wh,
                                                const unsigned short* __restrict__ wl,
                                                const unsigned short* __restrict__ b2th,
                                                const unsigned short* __restrict__ b2tl,
                                                unsigned short* __restrict__ A,
                                                float* __restrict__ cbuf) {
    int tid = threadIdx.x, wid = tid >> 6, lane = tid & 63;
    int lr = lane & 15, kg = lane >> 4;
    if (blockIdx.y == 16) {
        int rbase = blockIdx.x * 128 + wid * 32;
        f32x4 acc[2][4] = {};
#pragma unroll
        for (int kb = 0; kb < 2; ++kb) {
            bf16x8 ah[2], al[2];
#pragma unroll
            for (int mi = 0; mi < 2; ++mi) {
                size_t off = (size_t)(rbase + mi * 16 + lr) * 64 + kb * 32 + kg * 8;
                ah[mi] = *(const bf16x8*)(sh + off);
                al[mi] = *(const bf16x8*)(sl + off);
            }
#pragma unroll
            for (int ni = 0; ni < 4; ++ni) {
                size_t offB = (size_t)(ni * 16 + lr) * 64 + kb * 32 + kg * 8;
                bf16x8 bh = *(const bf16x8*)(b2th + offB);
                bf16x8 bl = *(const bf16x8*)(b2tl + offB);
#pragma unroll
                for (int mi = 0; mi < 2; ++mi) {
                    acc[mi][ni] = __builtin_amdgcn_mfma_f32_16x16x32_bf16(ah[mi], bh, acc[mi][ni], 0, 0, 0);
                    acc[mi][ni] = __builtin_amdgcn_mfma_f32_16x16x32_bf16(ah[mi], bl, acc[mi][ni], 0, 0, 0);
                    acc[mi][ni] = __builtin_amdgcn_mfma_f32_16x16x32_bf16(al[mi], bh, acc[mi][ni], 0, 0, 0);
                }
            }
        }
#pragma unroll
        for (int mi = 0; mi < 2; ++mi)
#pragma unroll
            for (int r = 0; r < 4; ++r)
#pragma unroll
                for (int ni = 0; ni < 4; ++ni)
                    cbuf[(size_t)(rbase + mi * 16 + kg * 4 + r) * 64 + ni * 16 + lr] = acc[mi][ni][r];
        return;
    }
    int mbase = blockIdx.x * 128 + (wid >> 1) * 64;
    int nbase = blockIdx.y * 128 + (wid & 1) * 64;
    f32x4 acc[4][4] = {};
#pragma unroll
    for (int kb = 0; kb < 2; ++kb) {
        bf16x8 ah[4], al[4], bh[4], bl[4];
#pragma unroll
        for (int mi = 0; mi < 4; ++mi) {
            size_t off = (size_t)(mbase + mi * 16 + lr) * 64 + kb * 32 + kg * 8;
            ah[mi] = *(const bf16x8*)(sh + off);
            al[mi] = *(const bf16x8*)(sl + off);
        }
#pragma unroll
        for (int ni = 0; ni < 4; ++ni) {
            size_t off = (size_t)(nbase + ni * 16 + lr) * 64 + kb * 32 + kg * 8;
            bh[ni] = *(const bf16x8*)(wh + off);
            bl[ni] = *(const bf16x8*)(wl + off);
        }
#pragma unroll
        for (int mi = 0; mi < 4; ++mi)
#pragma unroll
            for (int ni = 0; ni < 4; ++ni) {
                acc[mi][ni] = __builtin_amdgcn_mfma_f32_16x16x32_bf16(ah[mi], bh[ni], acc[mi][ni], 0, 0, 0);
                acc[mi][ni] = __builtin_amdgcn_mfma_f32_16x16x32_bf16(ah[mi], bl[ni], acc[mi][ni], 0, 0, 0);
                acc[mi][ni] = __builtin_amdgcn_mfma_f32_16x16x32_bf16(al[mi], bh[ni], acc[mi][ni], 0, 0, 0);
            }
    }
#pragma unroll
    for (int mi = 0; mi < 4; ++mi)
#pragma unroll
        for (int r = 0; r < 4; ++r) {
            size_t row = (size_t)(mbase + mi * 16 + kg * 4 + r) * 2048;
#pragma unroll
            for (int ni = 0; ni < 4; ++ni)
                A[row + nbase + ni * 16 + lr] = f2bf(acc[mi][ni][r]);
        }
}

// ================================================================ CSR edge message + scatter
__global__ __launch_bounds__(256) void k_edge(const int* __restrict__ ei,
                                              const int* __restrict__ startp,
                                              const int* __restrict__ srccnt,
                                              const int* __restrict__ eord,
                                              const float* __restrict__ h32,
                                              const unsigned short* __restrict__ A,
                                              const float* __restrict__ cbuf,
                                              float* __restrict__ agg) {
    int tid = threadIdx.x, wid = tid >> 6, o = tid & 63;
    int n = blockIdx.x * 4 + wid;
    int cnt = srccnt[n];
    if (cnt == 0) return;
    int beg = startp[n];
    float cv = cbuf[(size_t)n * DIM + o];
    const uint4* Ap = (const uint4*)(A + (size_t)n * 2048 + o * 32);
    uint4 a0 = Ap[0], a1 = Ap[1], a2 = Ap[2], a3 = Ap[3];
    for (int i = beg; i < beg + cnt; ++i) {
        int e = eord[i];
        int dst = ei[NE + e];
        const float4* hp = (const float4*)(h32 + (size_t)e * 32);
        float acc = cv;
        float4 hA = hp[0], hB = hp[1];
        acc += hA.x*bflo(a0.x) + hA.y*bfhi(a0.x) + hA.z*bflo(a0.y) + hA.w*bfhi(a0.y)
             + hB.x*bflo(a0.z) + hB.y*bfhi(a0.z) + hB.z*bflo(a0.w) + hB.w*bfhi(a0.w);
        hA = hp[2]; hB = hp[3];
        acc += hA.x*bflo(a1.x) + hA.y*bfhi(a1.x) + hA.z*bflo(a1.y) + hA.w*bfhi(a1.y)
             + hB.x*bflo(a1.z) + hB.y*bfhi(a1.z) + hB.z*bflo(a1.w) + hB.w*bfhi(a1.w);
        hA = hp[4]; hB = hp[5];
        acc += hA.x*bflo(a2.x) + hA.y*bfhi(a2.x) + hA.z*bflo(a2.y) + hA.w*bfhi(a2.y)
             + hB.x*bflo(a2.z) + hB.y*bfhi(a2.z) + hB.z*bflo(a2.w) + hB.w*bfhi(a2.w);
        hA = hp[6]; hB = hp[7];
        acc += hA.x*bflo(a3.x) + hA.y*bfhi(a3.x) + hA.z*bflo(a3.y) + hA.w*bfhi(a3.y)
             + hB.x*bflo(a3.z) + hB.y*bfhi(a3.z) + hB.z*bflo(a3.w) + hB.w*bfhi(a3.w);
        atomicAdd(&agg[(size_t)dst * DIM + o], acc);
    }
}

// ================================================================ fused update, 4 waves/block;
// on last iteration also produces oe/oc (edges_out folded) and skips s writes.
__global__ __launch_bounds__(256) void k_upd(
    float* __restrict__ s, unsigned short* __restrict__ shi, unsigned short* __restrict__ slo,
    float* __restrict__ agg, const float* __restrict__ deg, const float* __restrict__ conv_b,
    const unsigned short* __restrict__ rth, const unsigned short* __restrict__ rtl,
    const unsigned short* __restrict__ wihh, const unsigned short* __restrict__ wihl,
    const unsigned short* __restrict__ whhh, const unsigned short* __restrict__ whhl,
    const float* __restrict__ bih, const float* __restrict__ bhh,
    const float* __restrict__ x, const float* __restrict__ W1l, const float* __restrict__ b1l,
    const float* __restrict__ WUp, const float* __restrict__ bUp,
    float* __restrict__ oe, float* __restrict__ oc, int last)
{
    __shared__ unsigned short mh_l[16 * 64];
    __shared__ unsigned short ml_l[16 * 64];
    __shared__ float gl[16 * 384];
    __shared__ float oel[64];
    int tid = threadIdx.x;
    int wid = tid >> 6, lane = tid & 63;
    int lr = lane & 15, kg = lane >> 4;
    int m0 = blockIdx.x * 16;

    bf16x8 sa_h[2], sa_l[2];
#pragma unroll
    for (int kb = 0; kb < 2; ++kb) {
        size_t off = (size_t)(m0 + lr) * 64 + kb * 32 + kg * 8;
        sa_h[kb] = *(const bf16x8*)(shi + off);
        sa_l[kb] = *(const bf16x8*)(slo + off);
    }

    // ---- phase 1: m strip ni = wid
    f32x4 macc = {};
#pragma unroll
    for (int kb = 0; kb < 2; ++kb) {
        size_t offB = (size_t)(wid * 16 + lr) * 64 + kb * 32 + kg * 8;
        bf16x8 bh = *(const bf16x8*)(rth + offB);
        bf16x8 bl = *(const bf16x8*)(rtl + offB);
        macc = __builtin_amdgcn_mfma_f32_16x16x32_bf16(sa_h[kb], bh, macc, 0, 0, 0);
        macc = __builtin_amdgcn_mfma_f32_16x16x32_bf16(sa_h[kb], bl, macc, 0, 0, 0);
        macc = __builtin_amdgcn_mfma_f32_16x16x32_bf16(sa_l[kb], bh, macc, 0, 0, 0);
    }
#pragma unroll
    for (int r = 0; r < 4; ++r) {
        int row = m0 + kg * 4 + r;
        float inv = 1.f / fmaxf(deg[row], 1.f);
        int col = wid * 16 + lr;
        size_t idx = (size_t)row * 64 + col;
        float v = macc[r] + agg[idx] * inv + conv_b[col];
        agg[idx] = 0.f;                       // self-zero for next iteration
        v = fmaxf(v, 0.f);
        unsigned short h = f2bf(v);
        int loff = (kg * 4 + r) * 64 + col;
        mh_l[loff] = h; ml_l[loff] = f2bf(v - ubf(h));
    }
    __syncthreads();

    // ---- phase 2: 3 gi + 3 gh strips per wave
    bf16x8 ma_h[2], ma_l[2];
#pragma unroll
    for (int kb = 0; kb < 2; ++kb) {
        int loff = lr * 64 + kb * 32 + kg * 8;
        ma_h[kb] = *(const bf16x8*)(mh_l + loff);
        ma_l[kb] = *(const bf16x8*)(ml_l + loff);
    }
    f32x4 gacc[3] = {}, hacc[3] = {};
#pragma unroll
    for (int kb = 0; kb < 2; ++kb)
#pragma unroll
        for (int j = 0; j < 3; ++j) {
            int ni = wid * 3 + j;            // 0..11
            size_t offB = (size_t)(ni * 16 + lr) * 64 + kb * 32 + kg * 8;
            bf16x8 bh = *(const bf16x8*)(wihh + offB);
            bf16x8 bl = *(const bf16x8*)(wihl + offB);
            gacc[j] = __builtin_amdgcn_mfma_f32_16x16x32_bf16(ma_h[kb], bh, gacc[j], 0, 0, 0);
            gacc[j] = __builtin_amdgcn_mfma_f32_16x16x32_bf16(ma_h[kb], bl, gacc[j], 0, 0, 0);
            gacc[j] = __builtin_amdgcn_mfma_f32_16x16x32_bf16(ma_l[kb], bh, gacc[j], 0, 0, 0);
            bf16x8 ch = *(const bf16x8*)(whhh + offB);
            bf16x8 cl = *(const bf16x8*)(whhl + offB);
            hacc[j] = __builtin_amdgcn_mfma_f32_16x16x32_bf16(sa_h[kb], ch, hacc[j], 0, 0, 0);
            hacc[j] = __builtin_amdgcn_mfma_f32_16x16x32_bf16(sa_h[kb], cl, hacc[j], 0, 0, 0);
            hacc[j] = __builtin_amdgcn_mfma_f32_16x16x32_bf16(sa_l[kb], ch, hacc[j], 0, 0, 0);
        }
#pragma unroll
    for (int j = 0; j < 3; ++j)
#pragma unroll
        for (int r = 0; r < 4; ++r) {
            int row = kg * 4 + r;
            int col = (wid * 3 + j) * 16 + lr;      // 0..191
            gl[row * 384 + col] = gacc[j][r];
            gl[row * 384 + 192 + col] = hacc[j][r];
        }
    __syncthreads();

    // ---- phase 3: GRU elementwise; stash s_new into gl[row*384+d] (own ir slot)
#pragma unroll
    for (int k = 0; k < 4; ++k) {
        int item = tid + k * 256;           // 0..1023
        int row = item >> 6, d = item & 63;
        size_t idx = (size_t)(m0 + row) * 64 + d;
        const float* gr = gl + row * 384;
        float ir = gr[d], iz = gr[64 + d], in_ = gr[128 + d];
        float hr_ = gr[192 + d], hz = gr[256 + d], hn = gr[320 + d];
        float hv = s[idx];
        float rg = 1.f / (1.f + expf(-(ir + bih[d] + hr_ + bhh[d])));
        float z  = 1.f / (1.f + expf(-(iz + bih[64 + d] + hz + bhh[64 + d])));
        float nv = tanhf(in_ + bih[128 + d] + rg * (hn + bhh[128 + d]));
        float nh = (1.f - z) * nv + z * hv;
        if (!last) {
            s[idx] = nh;
            unsigned short hb = f2bf(nh);
            shi[idx] = hb; slo[idx] = f2bf(nh - ubf(hb));
        }
        gl[row * 384 + d] = nh;             // safe: this thread's own ir slot, already read
    }
    if (!last) return;
    __syncthreads();

    // ---- folded edges_out: oe = relu(s@W1l.T + b1l), oc = combine
    {
        int node16 = tid >> 4, j = tid & 15, t = j & 3, q = j >> 2;
        float p = 0.f;
#pragma unroll
        for (int i = 0; i < 16; ++i)
            p += gl[node16 * 384 + q * 16 + i] * W1l[t * 64 + q * 16 + i];
        p += __shfl_xor(p, 4);
        p += __shfl_xor(p, 8);
        if (q == 0) {
            float v = fmaxf(p + b1l[t], 0.f);
            oel[node16 * 4 + t] = v;
            oe[(size_t)(m0 + node16) * 4 + t] = v;
        }
    }
    __syncthreads();
#pragma unroll
    for (int k = 0; k < 4; ++k) {
        int item = tid + k * 256;
        int row = item >> 6, d = item & 63;
        int node = m0 + row;
        float sval = gl[row * 384 + d];
        float ocv;
        if (x[(size_t)node * FD] == 2.0f) {
            ocv = bUp[d];
#pragma unroll
            for (int t = 0; t < 4; ++t) ocv += oel[row * 4 + t] * WUp[d * 4 + t];
        } else {
            ocv = sval;
        }
        oc[(size_t)node * DIM + d] = ocv;
    }
}

// ================================================================ FGNet edge: me = oc[src] @ M[bond], atomic scatter
__global__ __launch_bounds__(256) void k_fgedge(const int* __restrict__ ei,
                                                const int* __restrict__ bond,
                                                const float* __restrict__ oc,
                                                const float* __restrict__ M,
                                                float* __restrict__ fg_agg) {
    __shared__ float so[4][64];
    int tid = threadIdx.x, w = tid >> 6, lane = tid & 63;
    int e = blockIdx.x * 4 + w;
    int src = ei[e], dst = ei[NE + e];
    int b = bond[e];
    so[w][lane] = oc[(size_t)src * DIM + lane];
    __syncthreads();
    float acc = 0.f;
    const float* Mp = M + b * DIM * DIM;
    for (int d = 0; d < 64; ++d) acc += so[w][d] * Mp[d * 64 + lane];
    atomicAdd(&fg_agg[(size_t)dst * DIM + lane], acc);
}

// ================================================================ final: msg_f -> msg_to_edge -> out_edges -> log_softmax
__global__ __launch_bounds__(256) void k_final(const float* __restrict__ fg_agg,
                                               const float* __restrict__ deg,
                                               const float* __restrict__ oe,
                                               const float* __restrict__ WDown,
                                               const float* __restrict__ bDown,
                                               const float* __restrict__ weight_e,
                                               const float* __restrict__ linWe,
                                               const float* __restrict__ linbe,
                                               float* __restrict__ out) {
    int tid = threadIdx.x, w = tid >> 6, lane = tid & 63;
    int node = blockIdx.x * 4 + w;
    float degc = fmaxf(deg[node], 1.f);
    float mf = fmaxf(fg_agg[(size_t)node * DIM + lane] / degc, 0.f);
    float mte[4];
#pragma unroll
    for (int t = 0; t < 4; ++t) {
        float p = mf * WDown[t * 64 + lane];
#pragma unroll
        for (int off = 32; off; off >>= 1) p += __shfl_xor(p, off);
        mte[t] = p + bDown[t];
    }
    float val[4];
    float mx = -1e30f;
#pragma unroll
    for (int t = 0; t < 4; ++t) {
        float acc = linbe[t];
#pragma unroll
        for (int t2 = 0; t2 < 4; ++t2) acc += weight_e[t2] * mte[t2] * linWe[t * 4 + t2];
        val[t] = oe[(size_t)node * 4 + t] + fmaxf(acc, 0.f);
        mx = fmaxf(mx, val[t]);
    }
    float lse = 0.f;
#pragma unroll
    for (int t = 0; t < 4; ++t) lse += expf(val[t] - mx);
    lse = logf(lse);
    if (lane < 4) out[(size_t)node * 4 + lane] = val[lane] - mx - lse;
}

// ================================================================ host
extern "C" void kernel_launch(void* const* d_in, const int* in_sizes, int n_in,
                              void* d_out, int out_size, void* d_ws, size_t ws_size,
                              hipStream_t stream) {
    const float* x       = (const float*)d_in[0];
    const int*   ei      = (const int*)  d_in[1];
    const float* ea      = (const float*)d_in[2];
    const float* W0      = (const float*)d_in[3];
    const float* b0      = (const float*)d_in[4];
    const float* nnW1    = (const float*)d_in[5];
    const float* nnb1    = (const float*)d_in[6];
    const float* nnW2    = (const float*)d_in[7];
    const float* nnb2    = (const float*)d_in[8];
    const float* root    = (const float*)d_in[9];
    const float* conv_b  = (const float*)d_in[10];
    const float* Wih     = (const float*)d_in[11];
    const float* Whh     = (const float*)d_in[12];
    const float* bih     = (const float*)d_in[13];
    const float* bhh     = (const float*)d_in[14];
    const float* W1l     = (const float*)d_in[15];
    const float* b1l     = (const float*)d_in[16];
    const float* WUp     = (const float*)d_in[17];
    const float* bUp     = (const float*)d_in[18];
    const float* WDown   = (const float*)d_in[19];
    const float* bDown   = (const float*)d_in[20];
    const float* U       = (const float*)d_in[21];
    const float* V       = (const float*)d_in[22];
    // d_in[23..25] weight/linW/linb: dead code (node-'out' branch never reaches output)
    const float* weight_e= (const float*)d_in[26];
    const float* linWe   = (const float*)d_in[27];
    const float* linbe   = (const float*)d_in[28];
    float* out = (float*)d_out;

    char* ws = (char*)d_ws;
    size_t off = 0;
    auto alloc = [&](size_t bytes) { size_t o = off; off = (off + bytes + 255) & ~(size_t)255; return o; };
    float* deg    = (float*)(ws + alloc((size_t)NN * 4));
    int*   srccnt = (int*)  (ws + alloc((size_t)NN * 4));            // adjacent to deg (one memset)
    float* agg    = (float*)(ws + alloc((size_t)NN * DIM * 4));      // contiguous with fg_agg
    float* fg_agg = (float*)(ws + alloc((size_t)NN * DIM * 4));      // (zeroed together in k_prep)
    float* s      = (float*)(ws + alloc((size_t)NN * DIM * 4));
    unsigned short* shi = (unsigned short*)(ws + alloc((size_t)NN * DIM * 2));
    unsigned short* slo = (unsigned short*)(ws + alloc((size_t)NN * DIM * 2));
    float* cbuf   = (float*)(ws + alloc((size_t)NN * DIM * 4));
    float* h32    = (float*)(ws + alloc((size_t)NE * 32 * 4));
    int*   bond   = (int*)  (ws + alloc((size_t)NE * 4));
    int*   startp = (int*)  (ws + alloc((size_t)(NN + 1) * 4));      // +1 sentinel
    int*   cursor = (int*)  (ws + alloc((size_t)NN * 4));
    int*   eord   = (int*)  (ws + alloc((size_t)NE * 4));
    float* oe     = (float*)(ws + alloc((size_t)NN * 4 * 4));
    float* oc     = (float*)(ws + alloc((size_t)NN * DIM * 4));
    float* Mbuf   = (float*)(ws + alloc((size_t)BT * DIM * DIM * 4));
    unsigned short* w2h = (unsigned short*)(ws + alloc((size_t)2048 * 64 * 2));
    unsigned short* w2l = (unsigned short*)(ws + alloc((size_t)2048 * 64 * 2));
    unsigned short* wihh = (unsigned short*)(ws + alloc((size_t)192 * 64 * 2));
    unsigned short* wihl = (unsigned short*)(ws + alloc((size_t)192 * 64 * 2));
    unsigned short* whhh = (unsigned short*)(ws + alloc((size_t)192 * 64 * 2));
    unsigned short* whhl = (unsigned short*)(ws + alloc((size_t)192 * 64 * 2));
    unsigned short* rth  = (unsigned short*)(ws + alloc((size_t)64 * 64 * 2));
    unsigned short* rtl  = (unsigned short*)(ws + alloc((size_t)64 * 64 * 2));
    unsigned short* b2th = (unsigned short*)(ws + alloc((size_t)64 * 64 * 2));
    unsigned short* b2tl = (unsigned short*)(ws + alloc((size_t)64 * 64 * 2));
    unsigned short* Abuf = (unsigned short*)(ws + alloc((size_t)NN * 2048 * 2));
    (void)n_in; (void)in_sizes; (void)out_size; (void)ws_size;

    hipMemsetAsync(deg, 0, (size_t)2 * NN * 4, stream);              // deg + srccnt only

    k_prep<<<2016, 256, 0, stream>>>(x, ei, ea, W0, b0, nnW1, nnb1,
                                     nnW2, Wih, Whh, root, nnb2, U, V,
                                     s, shi, slo, deg, srccnt, h32, bond,
                                     w2h, w2l, wihh, wihl, whhh, whhl,
                                     rth, rtl, b2th, b2tl, Mbuf, agg);
    k_scan<<<1, 1024, 0, stream>>>(srccnt, startp, cursor);
    k_scatter<<<NE / 256, 256, 0, stream>>>(ei, cursor, eord);

    for (int it = 0; it < 3; ++it) {
        k_gemm_A<<<dim3(NN / 128, 17), 256, 0, stream>>>(shi, slo, w2h, w2l, b2th, b2tl,
                                                         Abuf, cbuf);
        k_edge<<<NN / 4, 256, 0, stream>>>(ei, startp, srccnt, eord, h32, Abuf, cbuf, agg);
        k_upd<<<NN / 16, 256, 0, stream>>>(s, shi, slo, agg, deg, conv_b,
                                           rth, rtl, wihh, wihl, whhh, whhl, bih, bhh,
                                           x, W1l, b1l, WUp, bUp, oe, oc, it == 2);
    }

    k_fgedge<<<NE / 4, 256, 0, stream>>>(ei, bond, oc, Mbuf, fg_agg);
    k_final<<<NN / 4, 256, 0, stream>>>(fg_agg, deg, oe, WDown, bDown, weight_e, linWe, linbe, out);
}